// Round 1
// baseline (2045.301 us; speedup 1.0000x reference)
//
#include <hip/hip_runtime.h>
#include <math.h>

#define N_NODES   50000
#define N_EDGES   400000
#define NCH       16
#define RCUT      10.0f

// Kernel 1: per-edge geometry -> dists[e], unit[e][3]
__global__ void edge_geom_kernel(const float* __restrict__ pos,
                                 const int* __restrict__ src,
                                 const int* __restrict__ dst,
                                 float* __restrict__ dists,
                                 float* __restrict__ unit) {
    int e = blockIdx.x * blockDim.x + threadIdx.x;
    if (e >= N_EDGES) return;
    int s = src[e];
    int d = dst[e];
    float rx = pos[3 * s + 0] - pos[3 * d + 0];
    float ry = pos[3 * s + 1] - pos[3 * d + 1];
    float rz = pos[3 * s + 2] - pos[3 * d + 2];
    float dist = sqrtf(rx * rx + ry * ry + rz * rz);
    dists[e] = dist;
    float inv = 1.0f / dist;
    unit[3 * e + 0] = rx * inv;
    unit[3 * e + 1] = ry * inv;
    unit[3 * e + 2] = rz * inv;
}

// Kernel 2: one thread per (edge, channel). Computes the closed-form sum of all
// valid contractions and atomically scatters into out0/out1/out2 at src.
__global__ void edge_contract_kernel(const float* __restrict__ h0,
                                     const float* __restrict__ h1,
                                     const float* __restrict__ h2,
                                     const int* __restrict__ src,
                                     const int* __restrict__ dst,
                                     const float* __restrict__ dists,
                                     const float* __restrict__ unit,
                                     float* __restrict__ out0,
                                     float* __restrict__ out1,
                                     float* __restrict__ out2) {
    int t = blockIdx.x * blockDim.x + threadIdx.x;
    if (t >= N_EDGES * NCH) return;
    int e = t >> 4;       // edge
    int k = t & 15;       // channel
    int s = src[e];
    int d = dst[e];

    // Radial with the reference's faithful [K,E] -> [E,K] reshape:
    // flat index f = e*16+k reads element (f / E, f % E) of the [K,E] matrix.
    int f = t;
    int n_idx = f / N_EDGES;          // frequency index (0..15) -> n = n_idx+1
    int e_idx = f - n_idx * N_EDGES;  // which edge's distance is used
    float r = dists[e_idx];
    const float PI_F = 3.14159265358979323846f;
    float R = sqrtf(2.0f / RCUT) * sinf((float)(n_idx + 1) * PI_F * r / RCUT) / r;

    // unit vector of THIS edge
    float ux = unit[3 * e + 0];
    float uy = unit[3 * e + 1];
    float uz = unit[3 * e + 2];
    float u[3] = {ux, uy, uz};

    // gathered features at dst
    float A0 = h0[d * NCH + k];
    const float* a1p = h1 + ((size_t)d * NCH + k) * 3;
    float A1[3] = {a1p[0], a1p[1], a1p[2]};
    const float* a2p = h2 + ((size_t)d * NCH + k) * 9;
    float A2[9];
#pragma unroll
    for (int i = 0; i < 9; ++i) A2[i] = a2p[i];

    // derived scalars / vectors
    float d1 = A1[0] * ux + A1[1] * uy + A1[2] * uz;          // A1 . u
    float tA = A2[0] + A2[4] + A2[8];                          // tr(A2)
    float v[3], w[3];                                          // A2 u, A2^T u
#pragma unroll
    for (int m = 0; m < 3; ++m) {
        v[m] = A2[3 * m + 0] * ux + A2[3 * m + 1] * uy + A2[3 * m + 2] * uz;
        w[m] = A2[0 + m] * ux + A2[3 + m] * uy + A2[6 + m] * uz;
    }
    float q = ux * v[0] + uy * v[1] + uz * v[2];               // u^T A2 u

    // ---- rank-0 output ----
    float o0 = R * (2.0f * A0 + d1 + 2.0f * tA + 2.0f * q);
    atomicAdd(&out0[s * NCH + k], o0);

    // ---- rank-1 output ----
    float svw[3] = {v[0] + w[0], v[1] + w[1], v[2] + w[2]};
    float* o1p = out1 + ((size_t)s * NCH + k) * 3;
#pragma unroll
    for (int m = 0; m < 3; ++m) {
        float o1 = R * (A0 * u[m] + 2.0f * A1[m] + 2.0f * d1 * u[m] + svw[m] + tA * u[m]);
        atomicAdd(&o1p[m], o1);
    }

    // ---- rank-2 output ----
    float* o2p = out2 + ((size_t)s * NCH + k) * 9;
    float a0t = A0 + tA;
#pragma unroll
    for (int m = 0; m < 3; ++m) {
#pragma unroll
        for (int n = 0; n < 3; ++n) {
            float o2 = R * (a0t * u[m] * u[n] + A1[m] * u[n] + 2.0f * A2[3 * m + n]
                            + 2.0f * svw[m] * u[n]);
            atomicAdd(&o2p[3 * m + n], o2);
        }
    }
}

extern "C" void kernel_launch(void* const* d_in, const int* in_sizes, int n_in,
                              void* d_out, int out_size, void* d_ws, size_t ws_size,
                              hipStream_t stream) {
    const float* h0  = (const float*)d_in[0];
    const float* h1  = (const float*)d_in[1];
    const float* h2  = (const float*)d_in[2];
    const float* pos = (const float*)d_in[3];
    // d_in[4] = channel_weights: unused by the reference's actual dataflow
    const int* edge_index = (const int*)d_in[5];
    const int* src = edge_index;            // [E]
    const int* dst = edge_index + N_EDGES;  // [E]

    float* out = (float*)d_out;
    float* out0 = out;                                   // [N,16]
    float* out1 = out + (size_t)N_NODES * NCH;           // [N,16,3]
    float* out2 = out + (size_t)N_NODES * NCH * 4;       // [N,16,9]

    // workspace: dists [E], unit [E,3]
    float* dists = (float*)d_ws;
    float* unit  = dists + N_EDGES;

    // zero the accumulation output (harness poisons it with 0xAA)
    hipMemsetAsync(d_out, 0, (size_t)out_size * sizeof(float), stream);

    {
        dim3 block(256);
        dim3 grid((N_EDGES + 255) / 256);
        edge_geom_kernel<<<grid, block, 0, stream>>>(pos, src, dst, dists, unit);
    }
    {
        int total = N_EDGES * NCH;
        dim3 block(256);
        dim3 grid((total + 255) / 256);
        edge_contract_kernel<<<grid, block, 0, stream>>>(h0, h1, h2, src, dst,
                                                         dists, unit,
                                                         out0, out1, out2);
    }
}

// Round 2
// 228.153 us; speedup vs baseline: 8.9646x; 8.9646x over previous
//
#include <hip/hip_runtime.h>
#include <math.h>

#define N_NODES   50000
#define N_EDGES   400000
#define NCH       16
#define RCUT      10.0f

// ---------------- Kernel 1: per-edge geometry ----------------
__global__ void edge_geom_kernel(const float* __restrict__ pos,
                                 const int* __restrict__ src,
                                 const int* __restrict__ dst,
                                 float* __restrict__ dists,
                                 float* __restrict__ unit) {
    int e = blockIdx.x * blockDim.x + threadIdx.x;
    if (e >= N_EDGES) return;
    int s = src[e];
    int d = dst[e];
    float rx = pos[3 * s + 0] - pos[3 * d + 0];
    float ry = pos[3 * s + 1] - pos[3 * d + 1];
    float rz = pos[3 * s + 2] - pos[3 * d + 2];
    float dist = sqrtf(rx * rx + ry * ry + rz * rz);
    dists[e] = dist;
    float inv = 1.0f / dist;
    unit[3 * e + 0] = rx * inv;
    unit[3 * e + 1] = ry * inv;
    unit[3 * e + 2] = rz * inv;
}

// ---------------- CSR build ----------------
__global__ void hist_kernel(const int* __restrict__ src, int* __restrict__ cnt) {
    int e = blockIdx.x * blockDim.x + threadIdx.x;
    if (e >= N_EDGES) return;
    atomicAdd(&cnt[src[e]], 1);
}

// inclusive scan of 256-blocks; writes incl[] and per-block sums
__global__ void scan_blocks_kernel(const int* __restrict__ cnt,
                                   int* __restrict__ incl,
                                   int* __restrict__ bsum) {
    __shared__ int sh[256];
    int t = threadIdx.x;
    int i = blockIdx.x * 256 + t;
    int v = (i < N_NODES) ? cnt[i] : 0;
    sh[t] = v;
    __syncthreads();
    for (int s = 1; s < 256; s <<= 1) {
        int x = 0;
        if (t >= s) x = sh[t - s];
        __syncthreads();
        if (t >= s) sh[t] += x;
        __syncthreads();
    }
    if (i < N_NODES) incl[i] = sh[t];
    if (t == 255) bsum[blockIdx.x] = sh[255];
}

// scan the block sums (<=256 of them) -> exclusive block offsets
__global__ void scan_bsums_kernel(int* __restrict__ bsum, int nblocks) {
    __shared__ int sh[256];
    int t = threadIdx.x;
    int v = (t < nblocks) ? bsum[t] : 0;
    sh[t] = v;
    __syncthreads();
    for (int s = 1; s < 256; s <<= 1) {
        int x = 0;
        if (t >= s) x = sh[t - s];
        __syncthreads();
        if (t >= s) sh[t] += x;
        __syncthreads();
    }
    // exclusive: shift right
    if (t < nblocks) bsum[t] = sh[t] - v;
    __syncthreads();
}

// offsets[i] = incl[i]-cnt[i]+bexc[i/256]; cursor copy; offsets[N]=total
__global__ void finalize_offsets_kernel(const int* __restrict__ cnt,
                                        const int* __restrict__ incl,
                                        const int* __restrict__ bexc,
                                        int* __restrict__ offsets,
                                        int* __restrict__ cursor) {
    int i = blockIdx.x * blockDim.x + threadIdx.x;
    if (i >= N_NODES) return;
    int base = bexc[i >> 8];
    int off = incl[i] - cnt[i] + base;
    offsets[i] = off;
    cursor[i] = off;
    if (i == N_NODES - 1) offsets[N_NODES] = off + cnt[i];
}

__global__ void fill_csr_kernel(const int* __restrict__ src,
                                int* __restrict__ cursor,
                                int* __restrict__ csr) {
    int e = blockIdx.x * blockDim.x + threadIdx.x;
    if (e >= N_EDGES) return;
    int slot = atomicAdd(&cursor[src[e]], 1);
    csr[slot] = e;
}

// ---------------- Main: one thread per (node, channel) ----------------
__global__ void node_gather_kernel(const float* __restrict__ h0,
                                   const float* __restrict__ h1,
                                   const float* __restrict__ h2,
                                   const int* __restrict__ dst,
                                   const float* __restrict__ dists,
                                   const float* __restrict__ unit,
                                   const int* __restrict__ offsets,
                                   const int* __restrict__ csr,
                                   float* __restrict__ out0,
                                   float* __restrict__ out1,
                                   float* __restrict__ out2) {
    int t = blockIdx.x * blockDim.x + threadIdx.x;
    if (t >= N_NODES * NCH) return;
    int n = t >> 4;
    int k = t & 15;
    int beg = offsets[n];
    int end = offsets[n + 1];

    float acc0 = 0.0f;
    float acc1[3] = {0.0f, 0.0f, 0.0f};
    float acc2[9] = {0.0f, 0.0f, 0.0f, 0.0f, 0.0f, 0.0f, 0.0f, 0.0f, 0.0f};

    for (int i = beg; i < end; ++i) {
        int e = csr[i];
        int d = dst[e];

        // faithful [K,E]->[E,K] reshape of the Bessel RBF
        int f = e * NCH + k;
        int n_idx = f / N_EDGES;
        int e_idx = f - n_idx * N_EDGES;
        float r = dists[e_idx];
        // sqrt(2/RCUT) = 0.4472136, pi/RCUT = 0.31415927
        float R = 0.44721359549995794f * sinf((float)(n_idx + 1) * 0.3141592653589793f * r) / r;

        float ux = unit[3 * e + 0];
        float uy = unit[3 * e + 1];
        float uz = unit[3 * e + 2];
        float u[3] = {ux, uy, uz};

        float A0 = h0[d * NCH + k];
        const float* a1p = h1 + ((size_t)d * NCH + k) * 3;
        float A1[3] = {a1p[0], a1p[1], a1p[2]};
        const float* a2p = h2 + ((size_t)d * NCH + k) * 9;
        float A2[9];
#pragma unroll
        for (int j = 0; j < 9; ++j) A2[j] = a2p[j];

        float d1 = A1[0] * ux + A1[1] * uy + A1[2] * uz;   // A1.u
        float tA = A2[0] + A2[4] + A2[8];                   // tr(A2)
        float v[3], w[3];
#pragma unroll
        for (int m = 0; m < 3; ++m) {
            v[m] = A2[3 * m + 0] * ux + A2[3 * m + 1] * uy + A2[3 * m + 2] * uz;
            w[m] = A2[0 + m] * ux + A2[3 + m] * uy + A2[6 + m] * uz;
        }
        float q = ux * v[0] + uy * v[1] + uz * v[2];        // u^T A2 u

        acc0 += R * (2.0f * A0 + d1 + 2.0f * tA + 2.0f * q);

        float svw[3] = {v[0] + w[0], v[1] + w[1], v[2] + w[2]};
        float a0t = A0 + tA;
#pragma unroll
        for (int m = 0; m < 3; ++m) {
            acc1[m] += R * (A0 * u[m] + 2.0f * A1[m] + 2.0f * d1 * u[m] + svw[m] + tA * u[m]);
#pragma unroll
            for (int nn = 0; nn < 3; ++nn) {
                acc2[3 * m + nn] += R * (a0t * u[m] * u[nn] + A1[m] * u[nn]
                                         + 2.0f * A2[3 * m + nn] + 2.0f * svw[m] * u[nn]);
            }
        }
    }

    out0[t] = acc0;
    float* o1p = out1 + (size_t)t * 3;
#pragma unroll
    for (int m = 0; m < 3; ++m) o1p[m] = acc1[m];
    float* o2p = out2 + (size_t)t * 9;
#pragma unroll
    for (int m = 0; m < 9; ++m) o2p[m] = acc2[m];
}

extern "C" void kernel_launch(void* const* d_in, const int* in_sizes, int n_in,
                              void* d_out, int out_size, void* d_ws, size_t ws_size,
                              hipStream_t stream) {
    const float* h0  = (const float*)d_in[0];
    const float* h1  = (const float*)d_in[1];
    const float* h2  = (const float*)d_in[2];
    const float* pos = (const float*)d_in[3];
    // d_in[4] = channel_weights: dead in the reference dataflow
    const int* edge_index = (const int*)d_in[5];
    const int* src = edge_index;
    const int* dst = edge_index + N_EDGES;

    float* out = (float*)d_out;
    float* out0 = out;                                  // [N,16]
    float* out1 = out + (size_t)N_NODES * NCH;          // [N,16,3]
    float* out2 = out + (size_t)N_NODES * NCH * 4;      // [N,16,9]

    // workspace layout
    float* dists = (float*)d_ws;                        // [E]
    float* unit  = dists + N_EDGES;                     // [E,3]
    int* iws     = (int*)(unit + (size_t)N_EDGES * 3);
    int* cnt     = iws;                                 // [N]
    int* incl    = cnt + N_NODES;                       // [N]
    int* bsum    = incl + N_NODES;                      // [256]
    int* offsets = bsum + 256;                          // [N+1]
    int* cursor  = offsets + N_NODES + 1;               // [N]
    int* csr     = cursor + N_NODES;                    // [E]

    const int NB_NODES = (N_NODES + 255) / 256;   // 196
    const int NB_EDGES = (N_EDGES + 255) / 256;   // 1563

    hipMemsetAsync(cnt, 0, N_NODES * sizeof(int), stream);

    edge_geom_kernel<<<NB_EDGES, 256, 0, stream>>>(pos, src, dst, dists, unit);
    hist_kernel<<<NB_EDGES, 256, 0, stream>>>(src, cnt);
    scan_blocks_kernel<<<NB_NODES, 256, 0, stream>>>(cnt, incl, bsum);
    scan_bsums_kernel<<<1, 256, 0, stream>>>(bsum, NB_NODES);
    finalize_offsets_kernel<<<NB_NODES, 256, 0, stream>>>(cnt, incl, bsum, offsets, cursor);
    fill_csr_kernel<<<NB_EDGES, 256, 0, stream>>>(src, cursor, csr);

    const int TOTAL = N_NODES * NCH;
    node_gather_kernel<<<(TOTAL + 255) / 256, 256, 0, stream>>>(
        h0, h1, h2, dst, dists, unit, offsets, csr, out0, out1, out2);
}